// Round 8
// baseline (386.223 us; speedup 1.0000x reference)
//
#include <hip/hip_runtime.h>
#include <hip/hip_bf16.h>
#include <math.h>

#define D_ 3072
#define H_ 2048
#define N_ 16
#define BS_ 512
#define NT_ (H_ / 64)   // 32 K-tiles for the jtj pipeline

typedef short s16x8 __attribute__((ext_vector_type(8)));
typedef float f32x4v __attribute__((ext_vector_type(4)));
typedef __hip_bfloat16 bf16;

__device__ __forceinline__ void gload_lds16(const void* g, void* l) {
    __builtin_amdgcn_global_load_lds((const __attribute__((address_space(1))) void*)g,
                                     (__attribute__((address_space(3))) void*)l, 16, 0, 0);
}

__device__ __forceinline__ float bf2f(unsigned short u) {
    unsigned v = (unsigned)u << 16; float f; __builtin_memcpy(&f, &v, 4); return f;
}

// ---------------- split-K NT GEMM: C(f32) += A(M,K)*Bt(N,K)^T over K-chunk ----------------
__global__ __launch_bounds__(256) void mfma_nt_sk(
    const bf16* __restrict__ A, const bf16* __restrict__ Bt,
    float* __restrict__ C, int M, int N, int K, int KC)
{
    __shared__ __align__(16) bf16 As[128 * 32];
    __shared__ __align__(16) bf16 Bs[128 * 32];
    const int tid = threadIdx.x;
    const int w = tid >> 6, l = tid & 63;
    const int wr = w >> 1, wc = w & 1;
    const int m0 = blockIdx.y * 128, n0 = blockIdx.x * 128;
    const int kbeg = blockIdx.z * KC;

    f32x4v acc[4][4];
    #pragma unroll
    for (int a = 0; a < 4; ++a)
        #pragma unroll
        for (int b = 0; b < 4; ++b) acc[a][b] = (f32x4v){0.f, 0.f, 0.f, 0.f};

    const int srow = l >> 2;
    const int scol = (l & 3) * 8;

    for (int k0 = kbeg; k0 < kbeg + KC; k0 += 32) {
        #pragma unroll
        for (int q = 0; q < 2; ++q) {
            int r0 = w * 32 + q * 16;
            gload_lds16(&A[(size_t)(m0 + r0 + srow) * K + k0 + scol], &As[r0 * 32]);
            gload_lds16(&Bt[(size_t)(n0 + r0 + srow) * K + k0 + scol], &Bs[r0 * 32]);
        }
        __syncthreads();
        s16x8 af[4], bfr[4];
        #pragma unroll
        for (int mf = 0; mf < 4; ++mf)
            af[mf] = *(const s16x8*)&As[(wr * 64 + mf * 16 + (l & 15)) * 32 + (l >> 4) * 8];
        #pragma unroll
        for (int nf = 0; nf < 4; ++nf)
            bfr[nf] = *(const s16x8*)&Bs[(wc * 64 + nf * 16 + (l & 15)) * 32 + (l >> 4) * 8];
        #pragma unroll
        for (int mf = 0; mf < 4; ++mf)
            #pragma unroll
            for (int nf = 0; nf < 4; ++nf)
                acc[mf][nf] = __builtin_amdgcn_mfma_f32_16x16x32_bf16(af[mf], bfr[nf], acc[mf][nf], 0, 0, 0);
        __syncthreads();
    }

    #pragma unroll
    for (int mf = 0; mf < 4; ++mf)
        #pragma unroll
        for (int nf = 0; nf < 4; ++nf) {
            int n = n0 + wc * 64 + nf * 16 + (l & 15);
            #pragma unroll
            for (int r = 0; r < 4; ++r) {
                int m = m0 + wr * 64 + mf * 16 + (l >> 4) * 4 + r;
                atomicAdd(&C[(size_t)m * N + n], acc[mf][nf][r]);
            }
        }
}

// ---------------- epilogues ----------------
__global__ __launch_bounds__(256) void ep_ebf(const float* __restrict__ C,
    const float* __restrict__ bias, const float* __restrict__ X,
    bf16* __restrict__ Eout, int MN, int N)
{
    int base = (blockIdx.x * 256 + threadIdx.x) * 8;
    if (base < MN) {
        float4 c0 = *(const float4*)&C[base];
        float4 c1 = *(const float4*)&C[base + 4];
        float4 x0 = *(const float4*)&X[base];
        float4 x1 = *(const float4*)&X[base + 4];
        int n = base % N;
        float4 b0 = *(const float4*)&bias[n];
        float4 b1 = *(const float4*)&bias[n + 4];
        union { s16x8 v; bf16 e[8]; } u;
        u.e[0] = __float2bfloat16(x0.x - (c0.x + b0.x));
        u.e[1] = __float2bfloat16(x0.y - (c0.y + b0.y));
        u.e[2] = __float2bfloat16(x0.z - (c0.z + b0.z));
        u.e[3] = __float2bfloat16(x0.w - (c0.w + b0.w));
        u.e[4] = __float2bfloat16(x1.x - (c1.x + b1.x));
        u.e[5] = __float2bfloat16(x1.y - (c1.y + b1.y));
        u.e[6] = __float2bfloat16(x1.z - (c1.z + b1.z));
        u.e[7] = __float2bfloat16(x1.w - (c1.w + b1.w));
        *(s16x8*)&Eout[base] = u.v;
    }
}

__global__ __launch_bounds__(256) void ep_recon(const float* __restrict__ C,
    const float* __restrict__ bias, const float* __restrict__ X, float* __restrict__ rls)
{
    int m = blockIdx.x;
    float s = 0.f;
    for (int n = threadIdx.x * 4; n < D_; n += 1024) {
        float4 c = *(const float4*)&C[(size_t)m * D_ + n];
        float4 bb = *(const float4*)&bias[n];
        float4 xx = *(const float4*)&X[(size_t)m * D_ + n];
        float v0 = c.x + bb.x - xx.x, v1 = c.y + bb.y - xx.y;
        float v2 = c.z + bb.z - xx.z, v3 = c.w + bb.w - xx.w;
        s += v0 * v0 + v1 * v1 + v2 * v2 + v3 * v3;
    }
    __shared__ float red[4];
    int wid = threadIdx.x >> 6, lane = threadIdx.x & 63;
    #pragma unroll
    for (int off = 32; off; off >>= 1) s += __shfl_xor(s, off);
    if (lane == 0) red[wid] = s;
    __syncthreads();
    if (threadIdx.x == 0) rls[m] = red[0] + red[1] + red[2] + red[3];
}

// ---------------- 8-wave 256x256 deep-pipelined J-GEMM + J^T J ----------------
// 2 LDS buffers (dynamic 128 KiB). Per 64-K tile: 4 phases, each
// {ds_read frags; stage 1 half-tile of tile T+1; [vmcnt(0) at p3]; barrier;
//  setprio(1); 16 MFMA; setprio(0); barrier}. Stage order A0,A1,B0,B1 (HBM
// first, L2-resident B last -> the single per-tile drain is cheap).
// T2 swizzle: lds byte = row*128 + (colbyte ^ ((row&7)<<4)); staged via
// pre-swizzled global source (linear LDS dest, rule #21).
__global__ __launch_bounds__(512, 1) void jtj8(
    const bf16* __restrict__ Vt, const bf16* __restrict__ W2t,
    float* __restrict__ S, int nwg, int b0)
{
    extern __shared__ __align__(16) char smem[];
    char* Abase = smem;            // 2 buf x 256x64 bf16 = 65536 B
    char* Bbase = smem + 65536;    // 65536 B
    const int tid = threadIdx.x;
    const int w = tid >> 6, l = tid & 63;
    const int wr = w >> 2, wc = w & 3;

    const int bid = blockIdx.x;
    const int swz = (bid & 7) * (nwg >> 3) + (bid >> 3);   // nwg always % 8 == 0
    const int mb = swz / 12, nbk = swz % 12;
    const int m0 = mb * 256, n0 = nbk * 256;

    const int srow = tid >> 3;                                   // staging row within 64-row issue
    const int sswz = (((tid & 7) ^ ((tid >> 3) & 7)) << 4);      // pre-swizzled source colbyte

    f32x4v acc[8][4];
    #pragma unroll
    for (int i = 0; i < 8; ++i)
        #pragma unroll
        for (int j = 0; j < 4; ++j) acc[i][j] = (f32x4v){0.f, 0.f, 0.f, 0.f};

    // stage unit u (0=A-half0, 1=A-half1, 2=B-half0, 3=B-half1) of tile t into buffer bi
    auto STAGE = [&](int u, int t, int bi) {
        const char* gsrc;
        char* ldst;
        if (u < 2) {
            gsrc = (const char*)Vt + ((size_t)(m0 + u * 128 + srow) * H_ + t * 64) * 2 + sswz;
            ldst = Abase + bi * 32768 + u * 16384 + w * 1024;
        } else {
            gsrc = (const char*)W2t + ((size_t)(n0 + (u - 2) * 128 + srow) * H_ + t * 64) * 2 + sswz;
            ldst = Bbase + bi * 32768 + (u - 2) * 16384 + w * 1024;
        }
        gload_lds16(gsrc, ldst);
        gload_lds16(gsrc + (size_t)64 * H_ * 2, ldst + 8192);
    };

    // prologue: tile 0 -> buf 0, full drain once
    #pragma unroll
    for (int u = 0; u < 4; ++u) STAGE(u, 0, 0);
    asm volatile("s_waitcnt vmcnt(0)" ::: "memory");
    __builtin_amdgcn_s_barrier();
    __builtin_amdgcn_sched_barrier(0);

    for (int T = 0; T < NT_; ++T) {
        const int bi = T & 1;
        const char* Ab = Abase + bi * 32768;
        const char* Bb = Bbase + bi * 32768;
        #pragma unroll
        for (int p = 0; p < 4; ++p) {
            const int qa = p >> 1, qb = p & 1;
            s16x8 af[4][2], bfv[2][2];
            #pragma unroll
            for (int i = 0; i < 4; ++i) {
                int arow = wr * 128 + (qa * 4 + i) * 16 + (l & 15);
                #pragma unroll
                for (int kh = 0; kh < 2; ++kh)
                    af[i][kh] = *(const s16x8*)(Ab + arow * 128 +
                        ((kh * 64 + (l >> 4) * 16) ^ ((l & 7) << 4)));
            }
            #pragma unroll
            for (int j = 0; j < 2; ++j) {
                int brow = wc * 64 + (qb * 2 + j) * 16 + (l & 15);
                #pragma unroll
                for (int kh = 0; kh < 2; ++kh)
                    bfv[j][kh] = *(const s16x8*)(Bb + brow * 128 +
                        ((kh * 64 + (l >> 4) * 16) ^ ((l & 7) << 4)));
            }
            if (T + 1 < NT_) STAGE(p, T + 1, bi ^ 1);
            if (p == 3) asm volatile("s_waitcnt vmcnt(0)" ::: "memory");
            __builtin_amdgcn_s_barrier();
            __builtin_amdgcn_sched_barrier(0);
            __builtin_amdgcn_s_setprio(1);
            #pragma unroll
            for (int i = 0; i < 4; ++i)
                #pragma unroll
                for (int j = 0; j < 2; ++j) {
                    acc[qa * 4 + i][qb * 2 + j] = __builtin_amdgcn_mfma_f32_16x16x32_bf16(
                        af[i][0], bfv[j][0], acc[qa * 4 + i][qb * 2 + j], 0, 0, 0);
                    acc[qa * 4 + i][qb * 2 + j] = __builtin_amdgcn_mfma_f32_16x16x32_bf16(
                        af[i][1], bfv[j][1], acc[qa * 4 + i][qb * 2 + j], 0, 0, 0);
                }
            __builtin_amdgcn_s_setprio(0);
            __builtin_amdgcn_s_barrier();
            __builtin_amdgcn_sched_barrier(0);
        }
    }

    // ---- epilogue: J (bf16) -> LDS in 128-row halves, per-strip self-product ----
    __syncthreads();
    bf16* Jl = (bf16*)smem;     // 128 x 264 bf16 = 67.5 KB, overlays buffers
    const int bbase = b0 + mb * 16;
    #pragma unroll
    for (int h = 0; h < 2; ++h) {
        if (wr == h) {
            #pragma unroll
            for (int mf = 0; mf < 8; ++mf)
                #pragma unroll
                for (int nf = 0; nf < 4; ++nf) {
                    int rowb = mf * 16 + (l >> 4) * 4;
                    int col = wc * 64 + nf * 16 + (l & 15);
                    #pragma unroll
                    for (int r = 0; r < 4; ++r)
                        Jl[(rowb + r) * 264 + col] = __float2bfloat16(acc[mf][nf][r]);
                }
        }
        __syncthreads();
        f32x4v sp = (f32x4v){0.f, 0.f, 0.f, 0.f};
        #pragma unroll
        for (int kq = 0; kq < 8; ++kq) {
            s16x8 fr = *(const s16x8*)&Jl[((size_t)w * 16 + (l & 15)) * 264 + kq * 32 + (l >> 4) * 8];
            sp = __builtin_amdgcn_mfma_f32_16x16x32_bf16(fr, fr, sp, 0, 0, 0);
        }
        int bg = bbase + h * 8 + w;
        #pragma unroll
        for (int r = 0; r < 4; ++r)
            atomicAdd(&S[(size_t)bg * 256 + ((l >> 4) * 4 + r) * 16 + (l & 15)], sp[r]);
        __syncthreads();
    }
}

// ---------------- hessian via MFMA ----------------
__global__ __launch_bounds__(256) void hess_mfma(const float* __restrict__ t,
    const float* __restrict__ g, const bf16* __restrict__ W1b, float* __restrict__ S)
{
    const int w = threadIdx.x >> 6, l = threadIdx.x & 63;
    const int b = blockIdx.x * 4 + w;
    const int row = l & 15, kq = (l >> 4) * 8;

    f32x4v sp = (f32x4v){0.f, 0.f, 0.f, 0.f};
    for (int k0 = 0; k0 < H_; k0 += 32) {
        int kk = k0 + kq;
        s16x8 wf = *(const s16x8*)&W1b[(size_t)row * H_ + kk];
        float4 t0 = *(const float4*)&t[(size_t)b * H_ + kk];
        float4 t1 = *(const float4*)&t[(size_t)b * H_ + kk + 4];
        float4 g0 = *(const float4*)&g[(size_t)b * H_ + kk];
        float4 g1 = *(const float4*)&g[(size_t)b * H_ + kk + 4];
        float wv[8];
        wv[0] = 2.f * g0.x * t0.x * (1.f - t0.x * t0.x);
        wv[1] = 2.f * g0.y * t0.y * (1.f - t0.y * t0.y);
        wv[2] = 2.f * g0.z * t0.z * (1.f - t0.z * t0.z);
        wv[3] = 2.f * g0.w * t0.w * (1.f - t0.w * t0.w);
        wv[4] = 2.f * g1.x * t1.x * (1.f - t1.x * t1.x);
        wv[5] = 2.f * g1.y * t1.y * (1.f - t1.y * t1.y);
        wv[6] = 2.f * g1.z * t1.z * (1.f - t1.z * t1.z);
        wv[7] = 2.f * g1.w * t1.w * (1.f - t1.w * t1.w);
        union { s16x8 v; bf16 e[8]; } af;
        #pragma unroll
        for (int e = 0; e < 8; ++e)
            af.e[e] = __float2bfloat16(wv[e] * bf2f((unsigned short)wf[e]));
        sp = __builtin_amdgcn_mfma_f32_16x16x32_bf16(af.v, wf, sp, 0, 0, 0);
    }
    #pragma unroll
    for (int r = 0; r < 4; ++r)
        S[(size_t)b * 256 + ((l >> 4) * 4 + r) * 16 + (l & 15)] += sp[r];
}

// ---------------- fused prep: all casts in one launch ----------------
__global__ __launch_bounds__(256) void prep_all(
    const float* __restrict__ x, const float* __restrict__ enc_W1,
    const float* __restrict__ dec_W2, const float* __restrict__ dec_W1,
    bf16* __restrict__ x_bf, bf16* __restrict__ eW1t,
    bf16* __restrict__ W2t, bf16* __restrict__ W2b, bf16* __restrict__ W1b)
{
    __shared__ float tile[64][65];
    const int blk = blockIdx.x;
    const int tid = threadIdx.x;
    if (blk < 768) {
        int i = blk * 256 + tid;
        const float4* p = (const float4*)x + (size_t)i * 2;
        float4 a = p[0], b = p[1];
        union { s16x8 v; bf16 e[8]; } u;
        u.e[0] = __float2bfloat16(a.x); u.e[1] = __float2bfloat16(a.y);
        u.e[2] = __float2bfloat16(a.z); u.e[3] = __float2bfloat16(a.w);
        u.e[4] = __float2bfloat16(b.x); u.e[5] = __float2bfloat16(b.y);
        u.e[6] = __float2bfloat16(b.z); u.e[7] = __float2bfloat16(b.w);
        *(s16x8*)&x_bf[(size_t)i * 8] = u.v;
    } else if (blk < 768 + 1536) {
        int bid = blk - 768;
        int r0 = (bid % 48) * 64, c0 = (bid / 48) * 64;
        int tx = tid & 63, ty = tid >> 6;
        #pragma unroll
        for (int k = 0; k < 16; ++k) {
            int rr = ty * 16 + k;
            tile[rr][tx] = enc_W1[(size_t)(r0 + rr) * H_ + c0 + tx];
        }
        __syncthreads();
        #pragma unroll
        for (int k = 0; k < 16; ++k) {
            int cc = ty * 16 + k;
            eW1t[(size_t)(c0 + cc) * D_ + r0 + tx] = __float2bfloat16(tile[tx][cc]);
        }
    } else if (blk < 768 + 3072) {
        int bid = blk - 768 - 1536;
        int r0 = (bid % 32) * 64, c0 = (bid / 32) * 64;
        int tx = tid & 63, ty = tid >> 6;
        #pragma unroll
        for (int k = 0; k < 16; ++k) {
            int rr = ty * 16 + k;
            float v = dec_W2[(size_t)(r0 + rr) * D_ + c0 + tx];
            tile[rr][tx] = v;
            W2b[(size_t)(r0 + rr) * D_ + c0 + tx] = __float2bfloat16(v);
        }
        __syncthreads();
        #pragma unroll
        for (int k = 0; k < 16; ++k) {
            int cc = ty * 16 + k;
            W2t[(size_t)(c0 + cc) * H_ + r0 + tx] = __float2bfloat16(tile[tx][cc]);
        }
    } else {
        int i = (blk - 768 - 3072) * 256 + tid;
        if (i < N_ * H_ / 8) {
            const float4* p = (const float4*)dec_W1 + (size_t)i * 2;
            float4 a = p[0], b = p[1];
            union { s16x8 v; bf16 e[8]; } u;
            u.e[0] = __float2bfloat16(a.x); u.e[1] = __float2bfloat16(a.y);
            u.e[2] = __float2bfloat16(a.z); u.e[3] = __float2bfloat16(a.w);
            u.e[4] = __float2bfloat16(b.x); u.e[5] = __float2bfloat16(b.y);
            u.e[6] = __float2bfloat16(b.z); u.e[7] = __float2bfloat16(b.w);
            *(s16x8*)&W1b[(size_t)i * 8] = u.v;
        }
    }
}

// ---------------- zsig + build_t fused ----------------
__global__ __launch_bounds__(256) void zsig_t_kernel(const float* __restrict__ Ch,
    const float* __restrict__ enc_b1, const float* __restrict__ Wmu, const float* __restrict__ bmu,
    const float* __restrict__ Wls, const float* __restrict__ bls,
    const float* __restrict__ dW1, const float* __restrict__ db1,
    float* __restrict__ z_star, float* __restrict__ lsig, float* __restrict__ sigma,
    float* __restrict__ t, bf16* __restrict__ tb)
{
    const int b = blockIdx.x, tid = threadIdx.x;
    float acc[17];
    #pragma unroll
    for (int i = 0; i < 17; ++i) acc[i] = 0.f;
    for (int hh = tid; hh < H_; hh += 256) {
        float hv = tanhf(Ch[(size_t)b * H_ + hh] + enc_b1[hh]);
        const float* wr = &Wmu[(size_t)hh * 16];
        #pragma unroll
        for (int i = 0; i < 16; ++i) acc[i] += hv * wr[i];
        acc[16] += hv * Wls[hh];
    }
    __shared__ float red[17][4];
    __shared__ float zs[16];
    const int wid = tid >> 6, lane = tid & 63;
    #pragma unroll
    for (int i = 0; i < 17; ++i) {
        float v = acc[i];
        #pragma unroll
        for (int off = 32; off; off >>= 1) v += __shfl_xor(v, off);
        if (lane == 0) red[i][wid] = v;
    }
    __syncthreads();
    if (tid < 17) {
        float v = red[tid][0] + red[tid][1] + red[tid][2] + red[tid][3];
        if (tid < 16) { float z = v + bmu[tid]; zs[tid] = z; z_star[(size_t)b * 16 + tid] = z; }
        else { float ls = v + bls[0]; lsig[b] = ls; sigma[b] = expf(ls); }
    }
    __syncthreads();
    for (int hh = tid; hh < H_; hh += 256) {
        float a = db1[hh];
        #pragma unroll
        for (int i = 0; i < 16; ++i) a += zs[i] * dW1[(size_t)i * H_ + hh];
        float tv = tanhf(a);
        t[(size_t)b * H_ + hh] = tv;
        tb[(size_t)b * H_ + hh] = __float2bfloat16(tv);
    }
}

// t = tanh(z @ W1 + b1), bf16 out only
__global__ __launch_bounds__(256) void build_t(const float* __restrict__ z,
    const float* __restrict__ W1, const float* __restrict__ b1, bf16* __restrict__ tb)
{
    __shared__ float zs[16];
    int b = blockIdx.x, tid = threadIdx.x;
    if (tid < 16) zs[tid] = z[(size_t)b * 16 + tid];
    __syncthreads();
    for (int hh = tid; hh < H_; hh += 256) {
        float a = b1[hh];
        #pragma unroll
        for (int i = 0; i < 16; ++i) a += zs[i] * W1[(size_t)i * H_ + hh];
        tb[(size_t)b * H_ + hh] = __float2bfloat16(tanhf(a));
    }
}

// Vt[(b_local*16+i), h] = (1-t^2) * W1[i,h]  (bf16)
__global__ __launch_bounds__(256) void build_vt(const float* __restrict__ t,
    const float* __restrict__ W1, bf16* __restrict__ Vt, int b0)
{
    int bl = blockIdx.x, b = b0 + bl, tid = threadIdx.x;
    __shared__ float u[H_];
    for (int hh = tid; hh < H_; hh += 256) {
        float tv = t[(size_t)b * H_ + hh];
        u[hh] = 1.f - tv * tv;
    }
    __syncthreads();
    size_t base = (size_t)bl * 16 * H_;
    int hh = tid * 8;
    for (int i = 0; i < 16; ++i) {
        union { s16x8 v; bf16 e[8]; } pk;
        #pragma unroll
        for (int k = 0; k < 8; ++k)
            pk.e[k] = __float2bfloat16(u[hh + k] * W1[(size_t)i * H_ + hh + k]);
        *(s16x8*)&Vt[base + (size_t)i * H_ + hh] = pk.v;
    }
}

// ---------------- per-batch 16x16: barrier-free register solve ----------------
__global__ __launch_bounds__(64) void solve_kernel(const float* __restrict__ S,
    const float* __restrict__ sigma, const float* __restrict__ z_star,
    const float* __restrict__ eps, float* __restrict__ z_sample, float* __restrict__ d_out)
{
    const int lane = threadIdx.x;
    const int q = lane >> 4;
    const int j = lane & 15;
    const int b = blockIdx.x * 4 + q;

    const float sg = sigma[b];
    const float inv_s2 = 1.0f / (sg * sg);

    float a0[16], a[16];
    #pragma unroll
    for (int r = 0; r < 16; ++r) {
        a0[r] = S[(size_t)b * 256 + r * 16 + j] * inv_s2 + ((r == j) ? 1.0f : 0.0f);
        a[r] = a0[r];
    }

    #pragma unroll
    for (int k = 0; k < 14; ++k) {
        float x[16];
        #pragma unroll
        for (int r = 0; r < 16; ++r) x[r] = __shfl(a[k], r, 16);
        float sig2 = 0.f;
        #pragma unroll
        for (int r = 0; r < 16; ++r) if (r > k + 1) sig2 += x[r] * x[r];
        float x0 = x[k + 1];
        float normx = sqrtf(sig2 + x0 * x0);
        float alpha = (x0 >= 0.f) ? -normx : normx;
        float v[16];
        #pragma unroll
        for (int r = 0; r < 16; ++r)
            v[r] = (r <= k) ? 0.f : ((r == k + 1) ? x0 - alpha : x[r]);
        float vtv = 0.f;
        #pragma unroll
        for (int r = 0; r < 16; ++r) vtv += v[r] * v[r];
        float beta = (vtv > 1e-28f) ? 2.0f / vtv : 0.f;
        float sj = 0.f;
        #pragma unroll
        for (int r = 0; r < 16; ++r) sj += a[r] * v[r];
        float av[16];
        #pragma unroll
        for (int r = 0; r < 16; ++r) av[r] = __shfl(sj, r, 16);
        float vtav = 0.f;
        #pragma unroll
        for (int r = 0; r < 16; ++r) vtav += v[r] * av[r];
        float c = 0.5f * beta * vtav;
        float wv[16];
        #pragma unroll
        for (int r = 0; r < 16; ++r) wv[r] = beta * (av[r] - c * v[r]);
        float vj = (j <= k) ? 0.f : ((j == k + 1) ? a[k] - alpha : a[k]);
        float wj = beta * (sj - c * vj);
        #pragma unroll
        for (int r = 0; r < 16; ++r) a[r] -= v[r] * wj + wv[r] * vj;
    }

    float dg[16], eo[15];
    #pragma unroll
    for (int r = 0; r < 16; ++r) dg[r] = __shfl(a[r], r, 16);
    #pragma unroll
    for (int r = 0; r < 15; ++r) eo[r] = __shfl(a[r + 1], r, 16);

    float lo = 1e30f, hi = 1e30f;
    #pragma unroll
    for (int r = 0; r < 16; ++r) {
        float rad = ((r > 0) ? fabsf(eo[r - 1]) : 0.f) + ((r < 15) ? fabsf(eo[r]) : 0.f);
        lo = fminf(lo, dg[r] - rad);
        hi = fminf(hi, dg[r]);
    }
    lo -= 1e-4f; hi += 1e-4f;

    #pragma unroll
    for (int pass = 0; pass < 5; ++pass) {
        float step = (hi - lo) * (1.0f / 17.0f);
        float s = lo + step * (float)(j + 1);
        float qq = dg[0] - s;
        int cnt = (qq < 0.f) ? 1 : 0;
        #pragma unroll
        for (int i = 1; i < 16; ++i) {
            float denom = (fabsf(qq) < 1e-30f) ? -1e-30f : qq;
            qq = dg[i] - s - eo[i - 1] * eo[i - 1] / denom;
            cnt += (qq < 0.f) ? 1 : 0;
        }
        unsigned long long bal = __ballot(cnt >= 1);
        unsigned grp = (unsigned)((bal >> (q * 16)) & 0xffffull);
        int f = grp ? (__ffs(grp) - 1) : 16;
        float nlo = lo + step * (float)f;
        float nhi = (f < 16) ? (lo + step * (float)(f + 1)) : hi;
        lo = nlo; hi = nhi;
    }
    const float lam_min = 0.5f * (lo + hi);
    const float delta = 10.0f - lam_min;

    float bm[16];
    #pragma unroll
    for (int r = 0; r < 16; ++r) bm[r] = a0[r] + ((r == j) ? delta : 0.f);

    float ldsum = 0.f;
    #pragma unroll
    for (int kk = 0; kk < 16; ++kk) {
        float ck[16];
        #pragma unroll
        for (int r = 0; r < 16; ++r) ck[r] = __shfl(bm[kk], r, 16);
        float dkk = sqrtf(fmaxf(ck[kk], 1e-30f));
        float inv = 1.0f / dkk;
        ldsum += logf(dkk);
        float lfull[16];
        #pragma unroll
        for (int r = 0; r < 16; ++r) lfull[r] = ck[r] * inv;
        float lj = bm[kk] * inv;
        if (j == kk) {
            #pragma unroll
            for (int r = 0; r < 16; ++r) bm[r] = (r >= kk) ? lfull[r] : 0.f;
        } else if (j > kk) {
            #pragma unroll
            for (int r = 0; r < 16; ++r)
                if (r > kk) bm[r] -= lfull[r] * lj;
        }
    }

    float w[16];
    #pragma unroll
    for (int r = 0; r < 16; ++r) w[r] = 0.f;
    #pragma unroll
    for (int i = 0; i < 16; ++i) {
        float row[16];
        #pragma unroll
        for (int kx = 0; kx < 16; ++kx) row[kx] = __shfl(bm[i], kx, 16);
        float sacc = 0.f;
        #pragma unroll
        for (int kx = 0; kx < 16; ++kx) if (kx < i) sacc += row[kx] * w[kx];
        float invd = 1.0f / row[i];
        float val = (i == j) ? invd : (-sacc * invd);
        w[i] = (i >= j) ? val : 0.f;
    }

    float tsum = 0.f;
    #pragma unroll
    for (int r = 0; r < 16; ++r) tsum += w[r] * w[r];
    float zv = z_star[(size_t)b * 16 + j];
    float ep = eps[(size_t)b * 16 + j];
    float epsv[16];
    #pragma unroll
    for (int r = 0; r < 16; ++r) epsv[r] = __shfl(ep, r, 16);
    float zoff = 0.f;
    #pragma unroll
    for (int r = 0; r < 16; ++r) zoff += w[r] * epsv[r];
    z_sample[(size_t)b * 16 + j] = zv + zoff;

    float zsq = zv * zv;
    #pragma unroll
    for (int off = 1; off < 16; off <<= 1) {
        tsum += __shfl_xor(tsum, off);
        zsq  += __shfl_xor(zsq, off);
    }
    if (j == 0) {
        d_out[2 * 512 + b] = 0.5f * zsq + 0.5f * tsum;
        d_out[3 * 512 + b] = ldsum;
        d_out[4 * 512 + b] = sg;
    }
}

__global__ void finalize_kernel(const float* __restrict__ rlsum, const float* __restrict__ sigma,
    const float* __restrict__ lsig, float* __restrict__ d_out)
{
    int b = blockIdx.x * 256 + threadIdx.x;
    if (b < BS_) {
        float sg = sigma[b];
        float rl = rlsum[b] / (2.0f * sg * sg);
        float le = d_out[2 * 512 + b];
        float ld = d_out[3 * 512 + b];
        d_out[b] = (rl + le + ld) / 3072.0f + lsig[b];
        d_out[512 + b] = rl;
    }
}

extern "C" void kernel_launch(void* const* d_in, const int* in_sizes, int n_in,
                              void* d_out, int out_size, void* d_ws, size_t ws_size,
                              hipStream_t stream)
{
    const float* x       = (const float*)d_in[0];
    const float* eps     = (const float*)d_in[1];
    const float* enc_W1  = (const float*)d_in[2];
    const float* enc_b1  = (const float*)d_in[3];
    const float* enc_Wmu = (const float*)d_in[4];
    const float* enc_bmu = (const float*)d_in[5];
    const float* enc_Wls = (const float*)d_in[6];
    const float* enc_bls = (const float*)d_in[7];
    const float* dec_W1  = (const float*)d_in[8];
    const float* dec_b1  = (const float*)d_in[9];
    const float* dec_W2  = (const float*)d_in[10];
    const float* dec_b2  = (const float*)d_in[11];
    float* out = (float*)d_out;

    char* wsb = (char*)d_ws;
    size_t off = 0;
    auto alloc = [&](size_t bytes) -> void* {
        off = (off + 255) & ~(size_t)255;
        void* p = wsb + off;
        off += bytes;
        return p;
    };

    float* Ch   = (float*)alloc((size_t)BS_ * H_ * 4);
    float* Cd   = (float*)alloc((size_t)BS_ * D_ * 4);
    float* g    = (float*)alloc((size_t)BS_ * H_ * 4);
    float* S    = (float*)alloc((size_t)BS_ * 256 * 4);
    size_t zero_span = (size_t)((char*)(S + BS_ * 256) - (char*)Ch);

    float* t    = (float*)alloc((size_t)BS_ * H_ * 4);
    float* z_st = (float*)alloc((size_t)BS_ * 16 * 4);
    float* lsig = (float*)alloc(BS_ * 4);
    float* sigm = (float*)alloc(BS_ * 4);
    float* z_sm = (float*)alloc((size_t)BS_ * 16 * 4);
    float* rls  = (float*)alloc(BS_ * 4);
    bf16* x_bf  = (bf16*)alloc((size_t)BS_ * D_ * 2);
    bf16* eW1t  = (bf16*)alloc((size_t)H_ * D_ * 2);
    bf16* W2b   = (bf16*)alloc((size_t)H_ * D_ * 2);
    bf16* W2t   = (bf16*)alloc((size_t)D_ * H_ * 2);
    bf16* W1b   = (bf16*)alloc((size_t)N_ * H_ * 2);
    bf16* t_bf  = (bf16*)alloc((size_t)BS_ * H_ * 2);
    bf16* e_bf  = (bf16*)alloc((size_t)BS_ * D_ * 2);
    bf16* t2b   = (bf16*)alloc((size_t)BS_ * H_ * 2);

    int nb = 0;
    size_t base_off = off;
    const int cand[3] = {512, 128, 32};
    bf16* Vt = nullptr;
    for (int ci = 0; ci < 3; ++ci) {
        off = base_off;
        int n = cand[ci];
        bf16* vt = (bf16*)alloc((size_t)n * 16 * H_ * 2);
        if (off <= ws_size) { nb = n; Vt = vt; break; }
    }
    if (nb == 0) return;

    prep_all<<<dim3(768 + 3072 + 16), 256, 0, stream>>>(
        x, enc_W1, dec_W2, dec_W1, x_bf, eW1t, W2t, W2b, W1b);
    hipMemsetAsync(Ch, 0, zero_span, stream);

    mfma_nt_sk<<<dim3(H_ / 128, BS_ / 128, 4), 256, 0, stream>>>(
        x_bf, eW1t, Ch, BS_, H_, D_, D_ / 4);
    zsig_t_kernel<<<dim3(BS_), 256, 0, stream>>>(Ch, enc_b1, enc_Wmu, enc_bmu, enc_Wls, enc_bls,
        dec_W1, dec_b1, z_st, lsig, sigm, t, t_bf);
    mfma_nt_sk<<<dim3(D_ / 128, BS_ / 128, 4), 256, 0, stream>>>(
        t_bf, W2t, Cd, BS_, D_, H_, H_ / 4);
    ep_ebf<<<dim3(BS_ * D_ / 8 / 256), 256, 0, stream>>>(Cd, dec_b2, x, e_bf, BS_ * D_, D_);
    mfma_nt_sk<<<dim3(H_ / 128, BS_ / 128, 4), 256, 0, stream>>>(
        e_bf, W2b, g, BS_, H_, D_, D_ / 4);

    // S = J^T J (256^2 8-wave deep-pipelined, fused epilogue)
    for (int b0 = 0; b0 < BS_; b0 += nb) {
        build_vt<<<dim3(nb), 256, 0, stream>>>(t, dec_W1, Vt, b0);
        int Mb = nb * 16 / 256;
        jtj8<<<dim3(Mb * 12), 512, 131072, stream>>>(Vt, W2t, S, Mb * 12, b0);
    }
    hess_mfma<<<dim3(BS_ / 4), 256, 0, stream>>>(t, g, W1b, S);

    solve_kernel<<<dim3(BS_ / 4), 64, 0, stream>>>(S, sigm, z_st, eps, z_sm, out);
    build_t<<<dim3(BS_), 256, 0, stream>>>(z_sm, dec_W1, dec_b1, t2b);
    hipMemsetAsync(Cd, 0, (size_t)BS_ * D_ * 4, stream);
    mfma_nt_sk<<<dim3(D_ / 128, BS_ / 128, 4), 256, 0, stream>>>(
        t2b, W2t, Cd, BS_, D_, H_, H_ / 4);
    ep_recon<<<dim3(BS_), 256, 0, stream>>>(Cd, dec_b2, x, rls);
    finalize_kernel<<<dim3(2), 256, 0, stream>>>(rls, sigm, lsig, out);
}